// Round 3
// baseline (1853.973 us; speedup 1.0000x reference)
//
#include <hip/hip_runtime.h>

#define NN 200000
#define EE 400000
#define GG 4096

// ws layout (float offsets)
#define AGG_OFF 0
#define H1_OFF  (NN * 64)            // 12,800,000
#define SE_OFF  (H1_OFF + NN * 64)   // 25,600,000 (2*GG ints)

// ---------------- segment boundaries from sorted batch ----------------
__global__ void bounds_kernel(const int* __restrict__ batch, int* __restrict__ se) {
    int n = blockIdx.x * blockDim.x + threadIdx.x;
    if (n >= NN) return;
    int b = batch[n];
    if (n == 0 || batch[n - 1] != b) se[b] = n;                 // start
    if (n == NN - 1 || batch[n + 1] != b) se[GG + b] = n + 1;   // end
}

// ---------------- edge pass: m = relu(x[src] + ea@W + b); atomic scatter to agg[dst]
// one wave per edge; lane = output channel
__global__ __launch_bounds__(256) void edge_pass(const float* __restrict__ xin,
                                                 const int* __restrict__ ei,
                                                 const float* __restrict__ ea,
                                                 const float* __restrict__ ew,
                                                 const float* __restrict__ eb,
                                                 float* __restrict__ agg) {
    const int lane = threadIdx.x & 63;
    float Wr[16];
#pragma unroll
    for (int k = 0; k < 16; k++) Wr[k] = ew[k * 64 + lane];   // ew: (16,64)
    const float br = eb[lane];

    int w = blockIdx.x * 4 + (threadIdx.x >> 6);
    int nw = gridDim.x * 4;
    const float4* ea4 = (const float4*)ea;

    for (int e = w; e < EE; e += nw) {
        int s = __builtin_amdgcn_readfirstlane(ei[e]);
        int d = __builtin_amdgcn_readfirstlane(ei[EE + e]);
        float4 p0 = ea4[(size_t)e * 4 + 0];
        float4 p1 = ea4[(size_t)e * 4 + 1];
        float4 p2 = ea4[(size_t)e * 4 + 2];
        float4 p3 = ea4[(size_t)e * 4 + 3];
        float ev[16] = { p0.x, p0.y, p0.z, p0.w, p1.x, p1.y, p1.z, p1.w,
                         p2.x, p2.y, p2.z, p2.w, p3.x, p3.y, p3.z, p3.w };
        float acc = br;
#pragma unroll
        for (int k = 0; k < 16; k++) acc += ev[k] * Wr[k];
        float xv = xin[(size_t)s * 64 + lane];
        float m = fmaxf(acc + xv, 0.0f);
        atomicAdd(agg + (size_t)d * 64 + lane, m);
    }
}

// ---------------- node MLP layer 1: h1 = relu( relu((x+agg)@W1+b1) @ W2 + b2 )
// thread-per-node; t-chunk 8 keeps live set ~136 floats (no spill)
__global__ __launch_bounds__(256) void node1_kernel(const float* __restrict__ x,
                                                    const float* __restrict__ agg,
                                                    const float* __restrict__ W1,
                                                    const float* __restrict__ B1,
                                                    const float* __restrict__ W2,
                                                    const float* __restrict__ B2,
                                                    float* __restrict__ h1) {
    int n = blockIdx.x * 256 + threadIdx.x;
    if (n >= NN) return;

    float hin[64];
    const float4* x4 = (const float4*)(x + (size_t)n * 64);
    const float4* a4 = (const float4*)(agg + (size_t)n * 64);
#pragma unroll
    for (int q = 0; q < 16; q++) {
        float4 a = x4[q], b = a4[q];
        hin[4*q+0] = a.x + b.x; hin[4*q+1] = a.y + b.y;
        hin[4*q+2] = a.z + b.z; hin[4*q+3] = a.w + b.w;
    }

    float out[64];
#pragma unroll
    for (int c = 0; c < 64; c++) out[c] = B2[c];

#pragma unroll 1
    for (int jc = 0; jc < 64; jc += 8) {
        float t[8];
#pragma unroll
        for (int j = 0; j < 8; j++) t[j] = B1[jc + j];
#pragma unroll
        for (int k = 0; k < 64; k++) {
            float hv = hin[k];
#pragma unroll
            for (int j = 0; j < 8; j++) t[j] += hv * W1[k * 64 + jc + j];
        }
#pragma unroll
        for (int j = 0; j < 8; j++) t[j] = fmaxf(t[j], 0.0f);
#pragma unroll
        for (int j = 0; j < 8; j++) {
            float tv = t[j];
#pragma unroll
            for (int c = 0; c < 64; c++) out[c] += tv * W2[(jc + j) * 64 + c];
        }
    }

    float4* o4 = (float4*)(h1 + (size_t)n * 64);
#pragma unroll
    for (int q = 0; q < 16; q++) {
        float4 v;
        v.x = fmaxf(out[4*q+0], 0.0f);
        v.y = fmaxf(out[4*q+1], 0.0f);
        v.z = fmaxf(out[4*q+2], 0.0f);
        v.w = fmaxf(out[4*q+3], 0.0f);
        o4[q] = v;
    }
}

// ---------------- node MLP layer 2 (no outer relu), written IN PLACE:
//   hout[0:64) -> agg[n], hout[64:128) -> h1[n]
// two output-half passes, hidden layer recomputed per half: peak live
// hin[64]+out[64]+t[8] ~ 136 floats -> no scratch spill.
__global__ __launch_bounds__(256) void node2_kernel(float* __restrict__ h1,
                                                    float* __restrict__ agg,
                                                    const float* __restrict__ W1,
                                                    const float* __restrict__ B1,
                                                    const float* __restrict__ W2,
                                                    const float* __restrict__ B2) {
    int n = blockIdx.x * 256 + threadIdx.x;
    if (n >= NN) return;

    float hin[64];
    const float4* h4 = (const float4*)(h1 + (size_t)n * 64);
    const float4* a4 = (const float4*)(agg + (size_t)n * 64);
#pragma unroll
    for (int q = 0; q < 16; q++) {
        float4 a = h4[q], b = a4[q];
        hin[4*q+0] = a.x + b.x; hin[4*q+1] = a.y + b.y;
        hin[4*q+2] = a.z + b.z; hin[4*q+3] = a.w + b.w;
    }

#pragma unroll 1
    for (int half = 0; half < 2; half++) {
        const int co = half * 64;
        float out[64];
#pragma unroll
        for (int c = 0; c < 64; c++) out[c] = B2[co + c];

#pragma unroll 1
        for (int jc = 0; jc < 128; jc += 8) {
            float t[8];
#pragma unroll
            for (int j = 0; j < 8; j++) t[j] = B1[jc + j];
#pragma unroll
            for (int k = 0; k < 64; k++) {
                float hv = hin[k];
#pragma unroll
                for (int j = 0; j < 8; j++) t[j] += hv * W1[k * 128 + jc + j];
            }
#pragma unroll
            for (int j = 0; j < 8; j++) t[j] = fmaxf(t[j], 0.0f);
#pragma unroll
            for (int j = 0; j < 8; j++) {
                float tv = t[j];
#pragma unroll
                for (int c = 0; c < 64; c++) out[c] += tv * W2[(jc + j) * 128 + co + c];
            }
        }

        float* dst = (half == 0) ? (agg + (size_t)n * 64) : (h1 + (size_t)n * 64);
        float4* o4 = (float4*)dst;
#pragma unroll
        for (int q = 0; q < 16; q++) {
            float4 v;
            v.x = out[4*q+0]; v.y = out[4*q+1]; v.z = out[4*q+2]; v.w = out[4*q+3];
            o4[q] = v;
        }
    }
}

// ---------------- head: mean-pool (via segment bounds) + 5-layer MLP ----------------
__global__ __launch_bounds__(128) void head_kernel(const float* __restrict__ hlo,  // hout[0:64)
                                                   const float* __restrict__ hhi,  // hout[64:128)
                                                   const int* __restrict__ se,
                                                   const float* __restrict__ usr,
                                                   const float* __restrict__ h1w, const float* __restrict__ h1b,
                                                   const float* __restrict__ h2w, const float* __restrict__ h2b,
                                                   const float* __restrict__ h3w, const float* __restrict__ h3b,
                                                   const float* __restrict__ h4w, const float* __restrict__ h4b,
                                                   const float* __restrict__ h5w, const float* __restrict__ h5b,
                                                   float* __restrict__ out) {
    int g = blockIdx.x;
    int c = threadIdx.x;
    __shared__ float z0[140];
    __shared__ float z1[128];
    __shared__ float z2[64];
    __shared__ float z3[32];
    __shared__ float z4[16];

    int s = se[g], e = se[GG + g];
    float sum = 0.0f;
    if (c < 64) {
        for (int n = s; n < e; n++) sum += hlo[(size_t)n * 64 + c];
    } else {
        for (int n = s; n < e; n++) sum += hhi[(size_t)n * 64 + (c - 64)];
    }
    float cnt = fmaxf((float)(e - s), 1.0f);
    z0[c] = sum / cnt;
    if (c < 12) z0[128 + c] = usr[g * 12 + c];
    __syncthreads();

    // L1: 140 -> 128
    {
        float acc = h1b[c];
        for (int k = 0; k < 140; k++) acc += z0[k] * h1w[k * 128 + c];
        z1[c] = fmaxf(acc, 0.0f);
    }
    __syncthreads();
    // L2: 128 -> 64
    if (c < 64) {
        float acc = h2b[c];
        for (int k = 0; k < 128; k++) acc += z1[k] * h2w[k * 64 + c];
        z2[c] = fmaxf(acc, 0.0f);
    }
    __syncthreads();
    // L3: 64 -> 32
    if (c < 32) {
        float acc = h3b[c];
        for (int k = 0; k < 64; k++) acc += z2[k] * h3w[k * 32 + c];
        z3[c] = fmaxf(acc, 0.0f);
    }
    __syncthreads();
    // L4: 32 -> 16
    if (c < 16) {
        float acc = h4b[c];
        for (int k = 0; k < 32; k++) acc += z3[k] * h4w[k * 16 + c];
        z4[c] = fmaxf(acc, 0.0f);
    }
    __syncthreads();
    // L5: 16 -> 1
    if (c == 0) {
        float acc = h5b[0];
        for (int k = 0; k < 16; k++) acc += z4[k] * h5w[k];
        out[g] = acc;
    }
}

extern "C" void kernel_launch(void* const* d_in, const int* in_sizes, int n_in,
                              void* d_out, int out_size, void* d_ws, size_t ws_size,
                              hipStream_t stream) {
    const float* x    = (const float*)d_in[0];
    const int*   ei   = (const int*)d_in[1];
    const float* ea   = (const float*)d_in[2];
    const int*   batch= (const int*)d_in[3];
    const float* usr  = (const float*)d_in[4];
    const float* e1w  = (const float*)d_in[5],  *e1b  = (const float*)d_in[6];
    const float* n1w1 = (const float*)d_in[7],  *n1b1 = (const float*)d_in[8];
    const float* n1w2 = (const float*)d_in[9],  *n1b2 = (const float*)d_in[10];
    const float* e2w  = (const float*)d_in[11], *e2b  = (const float*)d_in[12];
    const float* n2w1 = (const float*)d_in[13], *n2b1 = (const float*)d_in[14];
    const float* n2w2 = (const float*)d_in[15], *n2b2 = (const float*)d_in[16];
    const float* h1w  = (const float*)d_in[17], *h1b  = (const float*)d_in[18];
    const float* h2w  = (const float*)d_in[19], *h2b  = (const float*)d_in[20];
    const float* h3w  = (const float*)d_in[21], *h3b  = (const float*)d_in[22];
    const float* h4w  = (const float*)d_in[23], *h4b  = (const float*)d_in[24];
    const float* h5w  = (const float*)d_in[25], *h5b  = (const float*)d_in[26];

    float* w   = (float*)d_ws;
    float* agg = w + AGG_OFF;
    float* h1  = w + H1_OFF;
    int*   se  = (int*)(w + SE_OFF);

    hipMemsetAsync(agg, 0, (size_t)NN * 64 * sizeof(float), stream);
    hipMemsetAsync(se, 0, (size_t)GG * 2 * sizeof(int), stream);

    bounds_kernel<<<(NN + 255) / 256, 256, 0, stream>>>(batch, se);

    edge_pass<<<4096, 256, 0, stream>>>(x, ei, ea, e1w, e1b, agg);
    node1_kernel<<<(NN + 255) / 256, 256, 0, stream>>>(x, agg, n1w1, n1b1, n1w2, n1b2, h1);

    hipMemsetAsync(agg, 0, (size_t)NN * 64 * sizeof(float), stream);
    edge_pass<<<4096, 256, 0, stream>>>(h1, ei, ea, e2w, e2b, agg);
    node2_kernel<<<(NN + 255) / 256, 256, 0, stream>>>(h1, agg, n2w1, n2b1, n2w2, n2b2);

    head_kernel<<<GG, 128, 0, stream>>>(agg, h1, se, usr,
                                        h1w, h1b, h2w, h2b, h3w, h3b, h4w, h4b, h5w, h5b,
                                        (float*)d_out);
}

// Round 4
// 1674.204 us; speedup vs baseline: 1.1074x; 1.1074x over previous
//
#include <hip/hip_runtime.h>

#define NN 200000
#define EE 400000
#define GG 4096

// ws layout (float offsets)
#define AGG_OFF 0
#define H1_OFF  (NN * 64)              // 12,800,000
#define SE_OFF  (H1_OFF + NN * 64)     // 25,600,000 (2*GG ints)
#define CHUNK_OFF (SE_OFF + 2 * GG)    // 25,608,192 : chunk buffer for hidden acts

// ---------------- segment boundaries from sorted batch ----------------
__global__ void bounds_kernel(const int* __restrict__ batch, int* __restrict__ se) {
    int n = blockIdx.x * blockDim.x + threadIdx.x;
    if (n >= NN) return;
    int b = batch[n];
    if (n == 0 || batch[n - 1] != b) se[b] = n;                 // start
    if (n == NN - 1 || batch[n + 1] != b) se[GG + b] = n + 1;   // end
}

// ---------------- edge pass: m = relu(x[src] + ea@W + b); atomic scatter to agg[dst]
// one wave per edge; lane = output channel
__global__ __launch_bounds__(256) void edge_pass(const float* __restrict__ xin,
                                                 const int* __restrict__ ei,
                                                 const float* __restrict__ ea,
                                                 const float* __restrict__ ew,
                                                 const float* __restrict__ eb,
                                                 float* __restrict__ agg) {
    const int lane = threadIdx.x & 63;
    float Wr[16];
#pragma unroll
    for (int k = 0; k < 16; k++) Wr[k] = ew[k * 64 + lane];   // ew: (16,64)
    const float br = eb[lane];

    int w = blockIdx.x * 4 + (threadIdx.x >> 6);
    int nw = gridDim.x * 4;
    const float4* ea4 = (const float4*)ea;

    for (int e = w; e < EE; e += nw) {
        int s = __builtin_amdgcn_readfirstlane(ei[e]);
        int d = __builtin_amdgcn_readfirstlane(ei[EE + e]);
        float4 p0 = ea4[(size_t)e * 4 + 0];
        float4 p1 = ea4[(size_t)e * 4 + 1];
        float4 p2 = ea4[(size_t)e * 4 + 2];
        float4 p3 = ea4[(size_t)e * 4 + 3];
        float ev[16] = { p0.x, p0.y, p0.z, p0.w, p1.x, p1.y, p1.z, p1.w,
                         p2.x, p2.y, p2.z, p2.w, p3.x, p3.y, p3.z, p3.w };
        float acc = br;
#pragma unroll
        for (int k = 0; k < 16; k++) acc += ev[k] * Wr[k];
        float xv = xin[(size_t)s * 64 + lane];
        float m = fmaxf(acc + xv, 0.0f);
        atomicAdd(agg + (size_t)d * 64 + lane, m);
    }
}

// ---------------- streaming dense layer: Y[r, c0:c0+CPT] = (relu?)(X[r]·W[:,c0:]+B)
// thread = (row, colgroup), colgroup fastest within wave:
//  - weight float4 loads coalesced across lanes (L1-hot small matrices)
//  - X row float4 loads dedup across the (64/CG) lanes sharing a row
//  - stores coalesced
// SPLITY: cols [0,64) -> Ylo, [64,128) -> Yhi (both row-stride 64)
template <int K, int CPT, int C, bool RELU, bool ADD2, bool SPLITY>
__global__ __launch_bounds__(256, 1) void mlp_kernel(const float* __restrict__ X,
                                                     const float* __restrict__ X2,
                                                     const float* __restrict__ W,
                                                     const float* __restrict__ Bv,
                                                     float* __restrict__ Ylo,
                                                     float* __restrict__ Yhi,
                                                     int rows) {
    constexpr int CG = C / CPT;
    int task = blockIdx.x * 256 + threadIdx.x;
    int row = task / CG;
    int cg  = task % CG;
    if (row >= rows) return;
    const int c0 = cg * CPT;

    float xr[K];
    {
        const float4* a = (const float4*)(X + (size_t)row * K);
        if (ADD2) {
            const float4* b = (const float4*)(X2 + (size_t)row * K);
#pragma unroll
            for (int q = 0; q < K / 4; q++) {
                float4 u = a[q], v = b[q];
                xr[4*q+0] = u.x + v.x; xr[4*q+1] = u.y + v.y;
                xr[4*q+2] = u.z + v.z; xr[4*q+3] = u.w + v.w;
            }
        } else {
#pragma unroll
            for (int q = 0; q < K / 4; q++) {
                float4 u = a[q];
                xr[4*q+0] = u.x; xr[4*q+1] = u.y; xr[4*q+2] = u.z; xr[4*q+3] = u.w;
            }
        }
    }

    float acc[CPT];
    {
        const float4* b4 = (const float4*)(Bv + c0);
#pragma unroll
        for (int j = 0; j < CPT / 4; j++) {
            float4 v = b4[j];
            acc[4*j+0] = v.x; acc[4*j+1] = v.y; acc[4*j+2] = v.z; acc[4*j+3] = v.w;
        }
    }

    const float* wp = W + c0;
#pragma unroll
    for (int k = 0; k < K; k++) {
        const float4* w4 = (const float4*)(wp + (size_t)k * C);
        float xv = xr[k];
#pragma unroll
        for (int j = 0; j < CPT / 4; j++) {
            float4 wv = w4[j];
            acc[4*j+0] += xv * wv.x; acc[4*j+1] += xv * wv.y;
            acc[4*j+2] += xv * wv.z; acc[4*j+3] += xv * wv.w;
        }
    }

    float* dst;
    if (SPLITY) dst = (c0 < 64 ? Ylo : Yhi) + (size_t)row * 64 + (c0 & 63);
    else        dst = Ylo + (size_t)row * C + c0;
    float4* y4 = (float4*)dst;
#pragma unroll
    for (int j = 0; j < CPT / 4; j++) {
        float4 v;
        v.x = RELU ? fmaxf(acc[4*j+0], 0.0f) : acc[4*j+0];
        v.y = RELU ? fmaxf(acc[4*j+1], 0.0f) : acc[4*j+1];
        v.z = RELU ? fmaxf(acc[4*j+2], 0.0f) : acc[4*j+2];
        v.w = RELU ? fmaxf(acc[4*j+3], 0.0f) : acc[4*j+3];
        y4[j] = v;
    }
}

// ---------------- head: mean-pool (via segment bounds) + 5-layer MLP ----------------
__global__ __launch_bounds__(128) void head_kernel(const float* __restrict__ hlo,  // hout[0:64)
                                                   const float* __restrict__ hhi,  // hout[64:128)
                                                   const int* __restrict__ se,
                                                   const float* __restrict__ usr,
                                                   const float* __restrict__ h1w, const float* __restrict__ h1b,
                                                   const float* __restrict__ h2w, const float* __restrict__ h2b,
                                                   const float* __restrict__ h3w, const float* __restrict__ h3b,
                                                   const float* __restrict__ h4w, const float* __restrict__ h4b,
                                                   const float* __restrict__ h5w, const float* __restrict__ h5b,
                                                   float* __restrict__ out) {
    int g = blockIdx.x;
    int c = threadIdx.x;
    __shared__ float z0[140];
    __shared__ float z1[128];
    __shared__ float z2[64];
    __shared__ float z3[32];
    __shared__ float z4[16];

    int s = se[g], e = se[GG + g];
    float sum = 0.0f;
    if (c < 64) {
        for (int n = s; n < e; n++) sum += hlo[(size_t)n * 64 + c];
    } else {
        for (int n = s; n < e; n++) sum += hhi[(size_t)n * 64 + (c - 64)];
    }
    float cnt = fmaxf((float)(e - s), 1.0f);
    z0[c] = sum / cnt;
    if (c < 12) z0[128 + c] = usr[g * 12 + c];
    __syncthreads();

    {
        float acc = h1b[c];
        for (int k = 0; k < 140; k++) acc += z0[k] * h1w[k * 128 + c];
        z1[c] = fmaxf(acc, 0.0f);
    }
    __syncthreads();
    if (c < 64) {
        float acc = h2b[c];
        for (int k = 0; k < 128; k++) acc += z1[k] * h2w[k * 64 + c];
        z2[c] = fmaxf(acc, 0.0f);
    }
    __syncthreads();
    if (c < 32) {
        float acc = h3b[c];
        for (int k = 0; k < 64; k++) acc += z2[k] * h3w[k * 32 + c];
        z3[c] = fmaxf(acc, 0.0f);
    }
    __syncthreads();
    if (c < 16) {
        float acc = h4b[c];
        for (int k = 0; k < 32; k++) acc += z3[k] * h4w[k * 16 + c];
        z4[c] = fmaxf(acc, 0.0f);
    }
    __syncthreads();
    if (c == 0) {
        float acc = h5b[0];
        for (int k = 0; k < 16; k++) acc += z4[k] * h5w[k];
        out[g] = acc;
    }
}

static inline int grid_for(long long tasks) { return (int)((tasks + 255) / 256); }

extern "C" void kernel_launch(void* const* d_in, const int* in_sizes, int n_in,
                              void* d_out, int out_size, void* d_ws, size_t ws_size,
                              hipStream_t stream) {
    const float* x    = (const float*)d_in[0];
    const int*   ei   = (const int*)d_in[1];
    const float* ea   = (const float*)d_in[2];
    const int*   batch= (const int*)d_in[3];
    const float* usr  = (const float*)d_in[4];
    const float* e1w  = (const float*)d_in[5],  *e1b  = (const float*)d_in[6];
    const float* n1w1 = (const float*)d_in[7],  *n1b1 = (const float*)d_in[8];
    const float* n1w2 = (const float*)d_in[9],  *n1b2 = (const float*)d_in[10];
    const float* e2w  = (const float*)d_in[11], *e2b  = (const float*)d_in[12];
    const float* n2w1 = (const float*)d_in[13], *n2b1 = (const float*)d_in[14];
    const float* n2w2 = (const float*)d_in[15], *n2b2 = (const float*)d_in[16];
    const float* h1w  = (const float*)d_in[17], *h1b  = (const float*)d_in[18];
    const float* h2w  = (const float*)d_in[19], *h2b  = (const float*)d_in[20];
    const float* h3w  = (const float*)d_in[21], *h3b  = (const float*)d_in[22];
    const float* h4w  = (const float*)d_in[23], *h4b  = (const float*)d_in[24];
    const float* h5w  = (const float*)d_in[25], *h5b  = (const float*)d_in[26];

    float* w    = (float*)d_ws;
    float* agg  = w + AGG_OFF;
    float* h1   = w + H1_OFF;
    int*   se   = (int*)(w + SE_OFF);
    float* cbuf = w + CHUNK_OFF;

    // chunk sizing from available workspace (deterministic across calls)
    long long wsFloats = (long long)(ws_size / 4);
    long long avail = wsFloats - CHUNK_OFF;
    if (avail < 64 * 4096LL) avail = 64 * 4096LL;   // last-ditch floor
    int cr1 = (int)(avail / 64);  if (cr1 > NN) cr1 = NN;   // node1 hidden rows (x64)
    int cr2 = (int)(avail / 128); if (cr2 > NN) cr2 = NN;   // node2 hidden rows (x128)
    cr1 &= ~255; if (cr1 < 256) cr1 = 256;
    cr2 &= ~255; if (cr2 < 256) cr2 = 256;

    hipMemsetAsync(agg, 0, (size_t)NN * 64 * sizeof(float), stream);
    hipMemsetAsync(se, 0, (size_t)GG * 2 * sizeof(int), stream);

    bounds_kernel<<<(NN + 255) / 256, 256, 0, stream>>>(batch, se);

    // ---- layer 1 ----
    edge_pass<<<4096, 256, 0, stream>>>(x, ei, ea, e1w, e1b, agg);
    for (int n0 = 0; n0 < NN; n0 += cr1) {
        int rows = (NN - n0 < cr1) ? (NN - n0) : cr1;
        // Htmp = relu((x+agg) @ n1w1 + n1b1)   [rows x 64]
        mlp_kernel<64, 16, 64, true, true, false><<<grid_for((long long)rows * 4), 256, 0, stream>>>(
            x + (size_t)n0 * 64, agg + (size_t)n0 * 64, n1w1, n1b1, cbuf, nullptr, rows);
        // h1 = relu(Htmp @ n1w2 + n1b2)        [rows x 64]
        mlp_kernel<64, 16, 64, true, false, false><<<grid_for((long long)rows * 4), 256, 0, stream>>>(
            cbuf, nullptr, n1w2, n1b2, h1 + (size_t)n0 * 64, nullptr, rows);
    }

    // ---- layer 2 ----
    hipMemsetAsync(agg, 0, (size_t)NN * 64 * sizeof(float), stream);
    edge_pass<<<4096, 256, 0, stream>>>(h1, ei, ea, e2w, e2b, agg);
    for (int n0 = 0; n0 < NN; n0 += cr2) {
        int rows = (NN - n0 < cr2) ? (NN - n0) : cr2;
        // H2 = relu((h1+agg) @ n2w1 + n2b1)    [rows x 128]
        mlp_kernel<64, 16, 128, true, true, false><<<grid_for((long long)rows * 8), 256, 0, stream>>>(
            h1 + (size_t)n0 * 64, agg + (size_t)n0 * 64, n2w1, n2b1, cbuf, nullptr, rows);
        // OUT = H2 @ n2w2 + n2b2, cols 0:64 -> agg rows, 64:128 -> h1 rows
        mlp_kernel<128, 8, 128, false, false, true><<<grid_for((long long)rows * 16), 256, 0, stream>>>(
            cbuf, nullptr, n2w2, n2b2, agg + (size_t)n0 * 64, h1 + (size_t)n0 * 64, rows);
    }

    head_kernel<<<GG, 128, 0, stream>>>(agg, h1, se, usr,
                                        h1w, h1b, h2w, h2b, h3w, h3b, h4w, h4b, h5w, h5b,
                                        (float*)d_out);
}

// Round 5
// 760.259 us; speedup vs baseline: 2.4386x; 2.2021x over previous
//
#include <hip/hip_runtime.h>

#define NN 200000
#define EE 400000
#define GG 4096

// ws layout (float offsets)
#define AGG_OFF 0
#define H1_OFF  (NN * 64)              // 12,800,000
#define SE_OFF  (H1_OFF + NN * 64)     // 25,600,000 (2*GG ints)
#define CHUNK_OFF (SE_OFF + 2 * GG)    // 25,608,192 : hidden-activation buffer (<=200k x 128)

// ---------------- segment boundaries from sorted batch ----------------
__global__ void bounds_kernel(const int* __restrict__ batch, int* __restrict__ se) {
    int n = blockIdx.x * blockDim.x + threadIdx.x;
    if (n >= NN) return;
    int b = batch[n];
    if (n == 0 || batch[n - 1] != b) se[b] = n;                 // start
    if (n == NN - 1 || batch[n + 1] != b) se[GG + b] = n + 1;   // end
}

// ---------------- edge pass: m = relu(x[src] + ea@W + b); atomic scatter to agg[dst]
// one wave per edge; lane = output channel
__global__ __launch_bounds__(256) void edge_pass(const float* __restrict__ xin,
                                                 const int* __restrict__ ei,
                                                 const float* __restrict__ ea,
                                                 const float* __restrict__ ew,
                                                 const float* __restrict__ eb,
                                                 float* __restrict__ agg) {
    const int lane = threadIdx.x & 63;
    float Wr[16];
#pragma unroll
    for (int k = 0; k < 16; k++) Wr[k] = ew[k * 64 + lane];   // ew: (16,64)
    const float br = eb[lane];

    int w = blockIdx.x * 4 + (threadIdx.x >> 6);
    int nw = gridDim.x * 4;
    const float4* ea4 = (const float4*)ea;

    for (int e = w; e < EE; e += nw) {
        int s = __builtin_amdgcn_readfirstlane(ei[e]);
        int d = __builtin_amdgcn_readfirstlane(ei[EE + e]);
        float4 p0 = ea4[(size_t)e * 4 + 0];
        float4 p1 = ea4[(size_t)e * 4 + 1];
        float4 p2 = ea4[(size_t)e * 4 + 2];
        float4 p3 = ea4[(size_t)e * 4 + 3];
        float ev[16] = { p0.x, p0.y, p0.z, p0.w, p1.x, p1.y, p1.z, p1.w,
                         p2.x, p2.y, p2.z, p2.w, p3.x, p3.y, p3.z, p3.w };
        float acc = br;
#pragma unroll
        for (int k = 0; k < 16; k++) acc += ev[k] * Wr[k];
        float xv = xin[(size_t)s * 64 + lane];
        float m = fmaxf(acc + xv, 0.0f);
        atomicAdd(agg + (size_t)d * 64 + lane, m);
    }
}

// ---------------- tiled dense layer with W in LDS ----------------
// Y = (relu?)( (X [+X2]) @ W + B ),  X:[rows x K], W:[K x C] (LDS-staged), Y:[rows x C]
// 256 threads; thread tile = RPT(8) rows x CPT(8) cols; W read via ds_read_b128
// (broadcast across same-col-group lanes, 2-way aliasing = free).
// ds-bytes/FMA = 4/RPT -> VALU-bound. No early return (barrier); tail rows:
// clamped loads + guarded stores.
// SPLITY: cols [0,64) -> Ylo, [64,128) -> Yhi (both row-stride 64).
template <int K, int C, bool RELU, bool ADD2, bool SPLITY>
__global__ __launch_bounds__(256) void gemm_kernel(const float* __restrict__ X,
                                                   const float* __restrict__ X2,
                                                   const float* __restrict__ W,
                                                   const float* __restrict__ Bv,
                                                   float* __restrict__ Ylo,
                                                   float* __restrict__ Yhi,
                                                   int rows) {
    constexpr int CPT = 8, RPT = 8;
    constexpr int COLG = C / CPT;        // 8 (C=64) or 16 (C=128)
    constexpr int ROWG = 256 / COLG;     // 32 or 16
    constexpr int BR = ROWG * RPT;       // 256 or 128 rows per block

    __shared__ float Bs[K * C];
    {
        const float4* wsrc = (const float4*)W;
        float4* wdst = (float4*)Bs;
#pragma unroll 1
        for (int i = threadIdx.x; i < K * C / 4; i += 256) wdst[i] = wsrc[i];
    }

    const int cg = threadIdx.x % COLG;
    const int rg = threadIdx.x / COLG;
    const int c0 = cg * CPT;
    const int rbase = blockIdx.x * BR + rg * RPT;

    int ridx[RPT];
#pragma unroll
    for (int r = 0; r < RPT; r++) {
        int rr = rbase + r;
        ridx[r] = (rr < rows) ? rr : (rows - 1);
    }

    float acc[RPT][CPT];
    {
        const float4* b4 = (const float4*)(Bv + c0);
        float4 v0 = b4[0], v1 = b4[1];
        float bias[CPT] = { v0.x, v0.y, v0.z, v0.w, v1.x, v1.y, v1.z, v1.w };
#pragma unroll
        for (int r = 0; r < RPT; r++)
#pragma unroll
            for (int j = 0; j < CPT; j++) acc[r][j] = bias[j];
    }

    __syncthreads();

#pragma unroll 1
    for (int k4 = 0; k4 < K; k4 += 4) {
        float4 a[RPT];
#pragma unroll
        for (int r = 0; r < RPT; r++) {
            float4 u = *(const float4*)(X + (size_t)ridx[r] * K + k4);
            if (ADD2) {
                float4 v = *(const float4*)(X2 + (size_t)ridx[r] * K + k4);
                u.x += v.x; u.y += v.y; u.z += v.z; u.w += v.w;
            }
            a[r] = u;
        }
#pragma unroll
        for (int kk = 0; kk < 4; kk++) {
            const float4* brow = (const float4*)(Bs + (k4 + kk) * C + c0);
            float4 w0 = brow[0], w1 = brow[1];
            float bv[CPT] = { w0.x, w0.y, w0.z, w0.w, w1.x, w1.y, w1.z, w1.w };
#pragma unroll
            for (int r = 0; r < RPT; r++) {
                float av = (kk == 0) ? a[r].x : (kk == 1) ? a[r].y : (kk == 2) ? a[r].z : a[r].w;
#pragma unroll
                for (int j = 0; j < CPT; j++) acc[r][j] += av * bv[j];
            }
        }
    }

#pragma unroll
    for (int r = 0; r < RPT; r++) {
        int rr = rbase + r;
        if (rr < rows) {
            float* dst;
            if (SPLITY) dst = (c0 < 64) ? (Ylo + (size_t)rr * 64 + c0)
                                        : (Yhi + (size_t)rr * 64 + (c0 - 64));
            else        dst = Ylo + (size_t)rr * C + c0;
            float4 v0, v1;
            v0.x = RELU ? fmaxf(acc[r][0], 0.0f) : acc[r][0];
            v0.y = RELU ? fmaxf(acc[r][1], 0.0f) : acc[r][1];
            v0.z = RELU ? fmaxf(acc[r][2], 0.0f) : acc[r][2];
            v0.w = RELU ? fmaxf(acc[r][3], 0.0f) : acc[r][3];
            v1.x = RELU ? fmaxf(acc[r][4], 0.0f) : acc[r][4];
            v1.y = RELU ? fmaxf(acc[r][5], 0.0f) : acc[r][5];
            v1.z = RELU ? fmaxf(acc[r][6], 0.0f) : acc[r][6];
            v1.w = RELU ? fmaxf(acc[r][7], 0.0f) : acc[r][7];
            ((float4*)dst)[0] = v0;
            ((float4*)dst)[1] = v1;
        }
    }
}

// ---------------- head: mean-pool (via segment bounds) + 5-layer MLP ----------------
__global__ __launch_bounds__(128) void head_kernel(const float* __restrict__ hlo,  // hout[0:64)
                                                   const float* __restrict__ hhi,  // hout[64:128)
                                                   const int* __restrict__ se,
                                                   const float* __restrict__ usr,
                                                   const float* __restrict__ h1w, const float* __restrict__ h1b,
                                                   const float* __restrict__ h2w, const float* __restrict__ h2b,
                                                   const float* __restrict__ h3w, const float* __restrict__ h3b,
                                                   const float* __restrict__ h4w, const float* __restrict__ h4b,
                                                   const float* __restrict__ h5w, const float* __restrict__ h5b,
                                                   float* __restrict__ out) {
    int g = blockIdx.x;
    int c = threadIdx.x;
    __shared__ float z0[140];
    __shared__ float z1[128];
    __shared__ float z2[64];
    __shared__ float z3[32];
    __shared__ float z4[16];

    int s = se[g], e = se[GG + g];
    float sum = 0.0f;
    if (c < 64) {
        for (int n = s; n < e; n++) sum += hlo[(size_t)n * 64 + c];
    } else {
        for (int n = s; n < e; n++) sum += hhi[(size_t)n * 64 + (c - 64)];
    }
    float cnt = fmaxf((float)(e - s), 1.0f);
    z0[c] = sum / cnt;
    if (c < 12) z0[128 + c] = usr[g * 12 + c];
    __syncthreads();

    {
        float acc = h1b[c];
        for (int k = 0; k < 140; k++) acc += z0[k] * h1w[k * 128 + c];
        z1[c] = fmaxf(acc, 0.0f);
    }
    __syncthreads();
    if (c < 64) {
        float acc = h2b[c];
        for (int k = 0; k < 128; k++) acc += z1[k] * h2w[k * 64 + c];
        z2[c] = fmaxf(acc, 0.0f);
    }
    __syncthreads();
    if (c < 32) {
        float acc = h3b[c];
        for (int k = 0; k < 64; k++) acc += z2[k] * h3w[k * 32 + c];
        z3[c] = fmaxf(acc, 0.0f);
    }
    __syncthreads();
    if (c < 16) {
        float acc = h4b[c];
        for (int k = 0; k < 32; k++) acc += z3[k] * h4w[k * 16 + c];
        z4[c] = fmaxf(acc, 0.0f);
    }
    __syncthreads();
    if (c == 0) {
        float acc = h5b[0];
        for (int k = 0; k < 16; k++) acc += z4[k] * h5w[k];
        out[g] = acc;
    }
}

extern "C" void kernel_launch(void* const* d_in, const int* in_sizes, int n_in,
                              void* d_out, int out_size, void* d_ws, size_t ws_size,
                              hipStream_t stream) {
    const float* x    = (const float*)d_in[0];
    const int*   ei   = (const int*)d_in[1];
    const float* ea   = (const float*)d_in[2];
    const int*   batch= (const int*)d_in[3];
    const float* usr  = (const float*)d_in[4];
    const float* e1w  = (const float*)d_in[5],  *e1b  = (const float*)d_in[6];
    const float* n1w1 = (const float*)d_in[7],  *n1b1 = (const float*)d_in[8];
    const float* n1w2 = (const float*)d_in[9],  *n1b2 = (const float*)d_in[10];
    const float* e2w  = (const float*)d_in[11], *e2b  = (const float*)d_in[12];
    const float* n2w1 = (const float*)d_in[13], *n2b1 = (const float*)d_in[14];
    const float* n2w2 = (const float*)d_in[15], *n2b2 = (const float*)d_in[16];
    const float* h1w  = (const float*)d_in[17], *h1b  = (const float*)d_in[18];
    const float* h2w  = (const float*)d_in[19], *h2b  = (const float*)d_in[20];
    const float* h3w  = (const float*)d_in[21], *h3b  = (const float*)d_in[22];
    const float* h4w  = (const float*)d_in[23], *h4b  = (const float*)d_in[24];
    const float* h5w  = (const float*)d_in[25], *h5b  = (const float*)d_in[26];

    float* w    = (float*)d_ws;
    float* agg  = w + AGG_OFF;
    float* h1   = w + H1_OFF;
    int*   se   = (int*)(w + SE_OFF);
    float* cbuf = w + CHUNK_OFF;

    hipMemsetAsync(agg, 0, (size_t)NN * 64 * sizeof(float), stream);
    hipMemsetAsync(se, 0, (size_t)GG * 2 * sizeof(int), stream);

    bounds_kernel<<<(NN + 255) / 256, 256, 0, stream>>>(batch, se);

    // ---- layer 1 ----
    edge_pass<<<4096, 256, 0, stream>>>(x, ei, ea, e1w, e1b, agg);
    // Htmp = relu((x+agg) @ n1w1 + n1b1)   [NN x 64], BR=256
    gemm_kernel<64, 64, true, true, false><<<(NN + 255) / 256, 256, 0, stream>>>(
        x, agg, n1w1, n1b1, cbuf, nullptr, NN);
    // h1 = relu(Htmp @ n1w2 + n1b2)        [NN x 64], BR=256
    gemm_kernel<64, 64, true, false, false><<<(NN + 255) / 256, 256, 0, stream>>>(
        cbuf, nullptr, n1w2, n1b2, h1, nullptr, NN);

    // ---- layer 2 ----
    hipMemsetAsync(agg, 0, (size_t)NN * 64 * sizeof(float), stream);
    edge_pass<<<4096, 256, 0, stream>>>(h1, ei, ea, e2w, e2b, agg);
    // H2 = relu((h1+agg) @ n2w1 + n2b1)    [NN x 128], BR=128
    gemm_kernel<64, 128, true, true, false><<<(NN + 127) / 128, 256, 0, stream>>>(
        h1, agg, n2w1, n2b1, cbuf, nullptr, NN);
    // OUT = H2 @ n2w2 + n2b2, cols 0:64 -> agg, 64:128 -> h1, BR=128
    gemm_kernel<128, 128, false, false, true><<<(NN + 127) / 128, 256, 0, stream>>>(
        cbuf, nullptr, n2w2, n2b2, agg, h1, NN);

    head_kernel<<<GG, 128, 0, stream>>>(agg, h1, se, usr,
                                        h1w, h1b, h2w, h2b, h3w, h3b, h4w, h4b, h5w, h5b,
                                        (float*)d_out);
}

// Round 6
// 606.976 us; speedup vs baseline: 3.0544x; 1.2525x over previous
//
#include <hip/hip_runtime.h>

#define NN 200000
#define EE 400000
#define GG 4096

// ws layout (float offsets)
#define AGG_OFF 0
#define H1_OFF  (NN * 64)              // 12,800,000
#define SE_OFF  (H1_OFF + NN * 64)     // 25,600,000 (2*GG ints)
#define CHUNK_OFF (SE_OFF + 2 * GG)    // 25,608,192 : hidden-activation buffer (200k x 128)

// ---------------- segment boundaries from sorted batch ----------------
__global__ void bounds_kernel(const int* __restrict__ batch, int* __restrict__ se) {
    int n = blockIdx.x * blockDim.x + threadIdx.x;
    if (n >= NN) return;
    int b = batch[n];
    if (n == 0 || batch[n - 1] != b) se[b] = n;                 // start
    if (n == NN - 1 || batch[n + 1] != b) se[GG + b] = n + 1;   // end
}

// ---------------- edge pass: m = relu(x[src] + ea@W + b); atomic scatter to agg[dst]
// one wave per edge; lane = output channel. agg is PRE-INITIALIZED with the node
// features (x or h1), so after this pass agg = x + sum(messages)  (GINE eps=0).
__global__ __launch_bounds__(256) void edge_pass(const float* __restrict__ xin,
                                                 const int* __restrict__ ei,
                                                 const float* __restrict__ ea,
                                                 const float* __restrict__ ew,
                                                 const float* __restrict__ eb,
                                                 float* __restrict__ agg) {
    const int lane = threadIdx.x & 63;
    float Wr[16];
#pragma unroll
    for (int k = 0; k < 16; k++) Wr[k] = ew[k * 64 + lane];   // ew: (16,64)
    const float br = eb[lane];

    int w = blockIdx.x * 4 + (threadIdx.x >> 6);
    int nw = gridDim.x * 4;
    const float4* ea4 = (const float4*)ea;

    for (int e = w; e < EE; e += nw) {
        int s = __builtin_amdgcn_readfirstlane(ei[e]);
        int d = __builtin_amdgcn_readfirstlane(ei[EE + e]);
        float4 p0 = ea4[(size_t)e * 4 + 0];
        float4 p1 = ea4[(size_t)e * 4 + 1];
        float4 p2 = ea4[(size_t)e * 4 + 2];
        float4 p3 = ea4[(size_t)e * 4 + 3];
        float ev[16] = { p0.x, p0.y, p0.z, p0.w, p1.x, p1.y, p1.z, p1.w,
                         p2.x, p2.y, p2.z, p2.w, p3.x, p3.y, p3.z, p3.w };
        float acc = br;
#pragma unroll
        for (int k = 0; k < 16; k++) acc += ev[k] * Wr[k];
        float xv = xin[(size_t)s * 64 + lane];
        float m = fmaxf(acc + xv, 0.0f);
        atomicAdd(agg + (size_t)d * 64 + lane, m);
    }
}

// ---------------- tiled dense layer, W staged in LDS (K-chunked), X prefetch ----
// Y = (relu?)( X @ W + B ),  X:[rows x K], W:[K x C], Y:[rows x C]
// 256 threads; thread tile = RPT(4) rows x 8 cols, cols split {cg*4, C/2+cg*4}
// -> ds_read_b128 with <=2-way bank alias (free), coalesced stores.
// Software pipeline: next k4's X fragments prefetched before current FMA block.
// No early return (barriers); tail rows: clamped loads + guarded stores.
// SPLITY: cols [0,C/2) -> Ylo, [C/2,C) -> Yhi (both row-stride 64).
template <int K, int C, bool RELU, bool SPLITY>
__global__ __launch_bounds__(256) void gemm_kernel(const float* __restrict__ X,
                                                   const float* __restrict__ W,
                                                   const float* __restrict__ Bv,
                                                   float* __restrict__ Ylo,
                                                   float* __restrict__ Yhi,
                                                   int rows) {
    constexpr int CPT = 8, RPT = 4;
    constexpr int COLG = C / CPT;        // 8 (C=64) or 16 (C=128)
    constexpr int ROWG = 256 / COLG;     // 32 or 16
    constexpr int BR = ROWG * RPT;       // 128 or 64 rows per block
    constexpr int KC = (K < 64) ? K : 64;  // K-chunk staged in LDS (<=32 KB)

    __shared__ float Bs[KC * C];

    const int cg = threadIdx.x % COLG;
    const int rg = threadIdx.x / COLG;
    const int c0a = cg * 4;
    const int c0b = C / 2 + cg * 4;
    const int rbase = blockIdx.x * BR + rg * RPT;

    const float* xptr[RPT];
#pragma unroll
    for (int r = 0; r < RPT; r++) {
        int rr = rbase + r;
        int ri = (rr < rows) ? rr : (rows - 1);
        xptr[r] = X + (size_t)ri * K;
    }

    float acc[RPT][CPT];
    {
        const float4* ba = (const float4*)(Bv + c0a);
        const float4* bb = (const float4*)(Bv + c0b);
        float4 v0 = ba[0], v1 = bb[0];
#pragma unroll
        for (int r = 0; r < RPT; r++) {
            acc[r][0] = v0.x; acc[r][1] = v0.y; acc[r][2] = v0.z; acc[r][3] = v0.w;
            acc[r][4] = v1.x; acc[r][5] = v1.y; acc[r][6] = v1.z; acc[r][7] = v1.w;
        }
    }

    float4 a_cur[RPT], a_nxt[RPT];
#pragma unroll
    for (int r = 0; r < RPT; r++) a_cur[r] = *(const float4*)(xptr[r]);

#pragma unroll 1
    for (int kc = 0; kc < K; kc += KC) {
        __syncthreads();   // previous chunk fully consumed before overwrite
        {
            const float4* wsrc = (const float4*)(W + (size_t)kc * C);
            float4* wdst = (float4*)Bs;
            for (int i = threadIdx.x; i < KC * C / 4; i += 256) wdst[i] = wsrc[i];
        }
        __syncthreads();

#pragma unroll 2
        for (int k4 = 0; k4 < KC; k4 += 4) {
            const int knext = kc + k4 + 4;
            if (knext < K) {
#pragma unroll
                for (int r = 0; r < RPT; r++)
                    a_nxt[r] = *(const float4*)(xptr[r] + knext);
            }
#pragma unroll
            for (int kk = 0; kk < 4; kk++) {
                const float4 w0 = *(const float4*)(Bs + (k4 + kk) * C + c0a);
                const float4 w1 = *(const float4*)(Bs + (k4 + kk) * C + c0b);
#pragma unroll
                for (int r = 0; r < RPT; r++) {
                    float av = (kk == 0) ? a_cur[r].x : (kk == 1) ? a_cur[r].y
                             : (kk == 2) ? a_cur[r].z : a_cur[r].w;
                    acc[r][0] += av * w0.x; acc[r][1] += av * w0.y;
                    acc[r][2] += av * w0.z; acc[r][3] += av * w0.w;
                    acc[r][4] += av * w1.x; acc[r][5] += av * w1.y;
                    acc[r][6] += av * w1.z; acc[r][7] += av * w1.w;
                }
            }
#pragma unroll
            for (int r = 0; r < RPT; r++) a_cur[r] = a_nxt[r];
        }
    }

#pragma unroll
    for (int r = 0; r < RPT; r++) {
        int rr = rbase + r;
        if (rr < rows) {
            float4 v0, v1;
            v0.x = RELU ? fmaxf(acc[r][0], 0.0f) : acc[r][0];
            v0.y = RELU ? fmaxf(acc[r][1], 0.0f) : acc[r][1];
            v0.z = RELU ? fmaxf(acc[r][2], 0.0f) : acc[r][2];
            v0.w = RELU ? fmaxf(acc[r][3], 0.0f) : acc[r][3];
            v1.x = RELU ? fmaxf(acc[r][4], 0.0f) : acc[r][4];
            v1.y = RELU ? fmaxf(acc[r][5], 0.0f) : acc[r][5];
            v1.z = RELU ? fmaxf(acc[r][6], 0.0f) : acc[r][6];
            v1.w = RELU ? fmaxf(acc[r][7], 0.0f) : acc[r][7];
            if (SPLITY) {
                *(float4*)(Ylo + (size_t)rr * 64 + c0a) = v0;
                *(float4*)(Yhi + (size_t)rr * 64 + (c0b - C / 2)) = v1;
            } else {
                *(float4*)(Ylo + (size_t)rr * C + c0a) = v0;
                *(float4*)(Ylo + (size_t)rr * C + c0b) = v1;
            }
        }
    }
}

// ---------------- head: mean-pool (via segment bounds) + 5-layer MLP ----------------
__global__ __launch_bounds__(128) void head_kernel(const float* __restrict__ hlo,  // hout[0:64)
                                                   const float* __restrict__ hhi,  // hout[64:128)
                                                   const int* __restrict__ se,
                                                   const float* __restrict__ usr,
                                                   const float* __restrict__ h1w, const float* __restrict__ h1b,
                                                   const float* __restrict__ h2w, const float* __restrict__ h2b,
                                                   const float* __restrict__ h3w, const float* __restrict__ h3b,
                                                   const float* __restrict__ h4w, const float* __restrict__ h4b,
                                                   const float* __restrict__ h5w, const float* __restrict__ h5b,
                                                   float* __restrict__ out) {
    int g = blockIdx.x;
    int c = threadIdx.x;
    __shared__ float z0[140];
    __shared__ float z1[128];
    __shared__ float z2[64];
    __shared__ float z3[32];
    __shared__ float z4[16];

    int s = se[g], e = se[GG + g];
    float sum = 0.0f;
    if (c < 64) {
        for (int n = s; n < e; n++) sum += hlo[(size_t)n * 64 + c];
    } else {
        for (int n = s; n < e; n++) sum += hhi[(size_t)n * 64 + (c - 64)];
    }
    float cnt = fmaxf((float)(e - s), 1.0f);
    z0[c] = sum / cnt;
    if (c < 12) z0[128 + c] = usr[g * 12 + c];
    __syncthreads();

    {
        float acc = h1b[c];
        for (int k = 0; k < 140; k++) acc += z0[k] * h1w[k * 128 + c];
        z1[c] = fmaxf(acc, 0.0f);
    }
    __syncthreads();
    if (c < 64) {
        float acc = h2b[c];
        for (int k = 0; k < 128; k++) acc += z1[k] * h2w[k * 64 + c];
        z2[c] = fmaxf(acc, 0.0f);
    }
    __syncthreads();
    if (c < 32) {
        float acc = h3b[c];
        for (int k = 0; k < 64; k++) acc += z2[k] * h3w[k * 32 + c];
        z3[c] = fmaxf(acc, 0.0f);
    }
    __syncthreads();
    if (c < 16) {
        float acc = h4b[c];
        for (int k = 0; k < 32; k++) acc += z3[k] * h4w[k * 16 + c];
        z4[c] = fmaxf(acc, 0.0f);
    }
    __syncthreads();
    if (c == 0) {
        float acc = h5b[0];
        for (int k = 0; k < 16; k++) acc += z4[k] * h5w[k];
        out[g] = acc;
    }
}

extern "C" void kernel_launch(void* const* d_in, const int* in_sizes, int n_in,
                              void* d_out, int out_size, void* d_ws, size_t ws_size,
                              hipStream_t stream) {
    const float* x    = (const float*)d_in[0];
    const int*   ei   = (const int*)d_in[1];
    const float* ea   = (const float*)d_in[2];
    const int*   batch= (const int*)d_in[3];
    const float* usr  = (const float*)d_in[4];
    const float* e1w  = (const float*)d_in[5],  *e1b  = (const float*)d_in[6];
    const float* n1w1 = (const float*)d_in[7],  *n1b1 = (const float*)d_in[8];
    const float* n1w2 = (const float*)d_in[9],  *n1b2 = (const float*)d_in[10];
    const float* e2w  = (const float*)d_in[11], *e2b  = (const float*)d_in[12];
    const float* n2w1 = (const float*)d_in[13], *n2b1 = (const float*)d_in[14];
    const float* n2w2 = (const float*)d_in[15], *n2b2 = (const float*)d_in[16];
    const float* h1w  = (const float*)d_in[17], *h1b  = (const float*)d_in[18];
    const float* h2w  = (const float*)d_in[19], *h2b  = (const float*)d_in[20];
    const float* h3w  = (const float*)d_in[21], *h3b  = (const float*)d_in[22];
    const float* h4w  = (const float*)d_in[23], *h4b  = (const float*)d_in[24];
    const float* h5w  = (const float*)d_in[25], *h5b  = (const float*)d_in[26];

    float* w    = (float*)d_ws;
    float* agg  = w + AGG_OFF;
    float* h1   = w + H1_OFF;
    int*   se   = (int*)(w + SE_OFF);
    float* cbuf = w + CHUNK_OFF;

    const size_t featBytes = (size_t)NN * 64 * sizeof(float);

    hipMemsetAsync(se, 0, (size_t)GG * 2 * sizeof(int), stream);
    bounds_kernel<<<(NN + 255) / 256, 256, 0, stream>>>(batch, se);

    // ---- layer 1 ----  agg := x, then agg += messages
    hipMemcpyAsync(agg, x, featBytes, hipMemcpyDeviceToDevice, stream);
    edge_pass<<<8192, 256, 0, stream>>>(x, ei, ea, e1w, e1b, agg);
    // Htmp = relu(agg @ n1w1 + n1b1)   [NN x 64], BR=128
    gemm_kernel<64, 64, true, false><<<(NN + 127) / 128, 256, 0, stream>>>(
        agg, n1w1, n1b1, cbuf, nullptr, NN);
    // h1 = relu(Htmp @ n1w2 + n1b2)    [NN x 64], BR=128
    gemm_kernel<64, 64, true, false><<<(NN + 127) / 128, 256, 0, stream>>>(
        cbuf, n1w2, n1b2, h1, nullptr, NN);

    // ---- layer 2 ----  agg := h1, then agg += messages
    hipMemcpyAsync(agg, h1, featBytes, hipMemcpyDeviceToDevice, stream);
    edge_pass<<<8192, 256, 0, stream>>>(h1, ei, ea, e2w, e2b, agg);
    // H2 = relu(agg @ n2w1 + n2b1)     [NN x 128], BR=64
    gemm_kernel<64, 128, true, false><<<(NN + 63) / 64, 256, 0, stream>>>(
        agg, n2w1, n2b1, cbuf, nullptr, NN);
    // OUT = H2 @ n2w2 + n2b2, cols 0:64 -> agg, 64:128 -> h1, BR=64
    gemm_kernel<128, 128, false, true><<<(NN + 63) / 64, 256, 0, stream>>>(
        cbuf, n2w2, n2b2, agg, h1, NN);

    head_kernel<<<GG, 128, 0, stream>>>(agg, h1, se, usr,
                                        h1w, h1b, h2w, h2b, h3w, h3b, h4w, h4b, h5w, h5b,
                                        (float*)d_out);
}